// Round 5
// baseline (173.921 us; speedup 1.0000x reference)
//
#include <hip/hip_runtime.h>

// Frames [B, T, C, H, W] = [8, 8, 3, 256, 256] fp32
// (Resubmission of round-4 kernel: bench infra failed, no measurement.)
#define BB 8
#define TT 8
#define NPAIR (TT - 1)               // 7
#define HH 256
#define WW 256
#define FRAME_PIX (HH * WW)
#define RROWS 4                      // rows per wave-item
#define NSTRIP (HH / RROWS)          // 64 strips per frame pair
#define NITEM (BB * NPAIR * NSTRIP)  // 3584 wave items
#define NBLK (NITEM / 4)             // 896 blocks x 4 waves
#define EPS 1e-3f
#define INV_N (1.0f / (float)((size_t)BB * NPAIR * 2 * HH * WW))

__device__ __forceinline__ float4 ld4(const float* __restrict__ p) {
    return *reinterpret_cast<const float4*>(p);
}
__device__ __forceinline__ float4 gray4(const float4 r, const float4 g, const float4 b) {
    float4 o;
    o.x = 0.2989f * r.x + 0.587f * g.x + 0.114f * b.x;
    o.y = 0.2989f * r.y + 0.587f * g.y + 0.114f * b.y;
    o.z = 0.2989f * r.z + 0.587f * g.z + 0.114f * b.z;
    o.w = 0.2989f * r.w + 0.587f * g.w + 0.114f * b.w;
    return o;
}

// One gray row as seen by a lane: 4 center px + left/right halo scalars
// fetched from neighbor lanes via shuffle (image edges zero-padded).
struct GRow { float l; float4 g; float r; };

__device__ __forceinline__ GRow mk_grow(const float4 gg, const int lane) {
    GRow o;
    o.g = gg;
    const float lw = __shfl_up(gg.w, 1, 64);
    const float rx = __shfl_down(gg.x, 1, 64);
    o.l = (lane == 0) ? 0.f : lw;
    o.r = (lane == 63) ? 0.f : rx;
    return o;
}

__device__ __forceinline__ void win6(const GRow& a, float w[6]) {
    w[0] = a.l; w[1] = a.g.x; w[2] = a.g.y; w[3] = a.g.z; w[4] = a.g.w; w[5] = a.r;
}

// Load the 3 channels of one row (4 px per lane); wave-uniform validity
// check implements the conv zero padding for rows outside the image.
__device__ __forceinline__ void ld3(const float* __restrict__ base, const int y,
                                    const int X, float4& c0, float4& c1, float4& c2) {
    if ((unsigned)y < (unsigned)HH) {
        const float* q = base + (size_t)y * WW + X;
        c0 = ld4(q); c1 = ld4(q + FRAME_PIX); c2 = ld4(q + 2 * FRAME_PIX);
    } else {
        c0 = make_float4(0.f, 0.f, 0.f, 0.f); c1 = c0; c2 = c0;
    }
}

// Barrier-free flow loss: one WAVE per (batch, pair, 4-row strip).
// 64 lanes x 4 px span the full 256-px row. Gray rows roll through a
// 3-slot register window; x-halo via lane shuffles; g1 raw channels kept
// one iteration for motion-mag. No LDS, no __syncthreads: waves free-run
// so resident waves keep the memory pipe continuously busy instead of
// the load/compute cohort phases of the block-tile version (~40us pin).
// __launch_bounds__(256,4): 128-VGPR cap -> 16 waves/CU, no spill
// (est. peak live ~115 VGPR).
__global__ __launch_bounds__(256, 4) void flow_loss_kernel(
    const float* __restrict__ pred, const float* __restrict__ gt,
    float* __restrict__ partial)
{
    const int tid   = threadIdx.x;
    const int lane  = tid & 63;
    const int item  = blockIdx.x * 4 + (tid >> 6);   // 0..3583
    const int strip = item & (NSTRIP - 1);
    const int pbt   = item >> 6;                     // 0..55
    const int b     = pbt / NPAIR;
    const int t     = pbt - b * NPAIR;

    const size_t fs = (size_t)3 * FRAME_PIX;
    const float* p1 = pred + ((size_t)b * TT + t) * fs;
    const float* g1 = gt   + ((size_t)b * TT + t) * fs;
    const float* p2 = p1 + fs;
    const float* g2 = g1 + fs;

    const int X  = lane * 4;
    const int y0 = strip * RROWS;

    GRow rp[3], rg[3];          // rolling gray rows: pred(t), gt(t)
    float4 k0, k1, k2;          // raw gt(t) channels of current output row

    // ---- prologue: gray rows y0-1 (slot 0) and y0 (slot 1) ----
    {
        float4 a0, a1, a2, c0, c1, c2;
        ld3(p1, y0 - 1, X, a0, a1, a2);
        ld3(g1, y0 - 1, X, c0, c1, c2);
        rp[0] = mk_grow(gray4(a0, a1, a2), lane);
        rg[0] = mk_grow(gray4(c0, c1, c2), lane);
        ld3(p1, y0, X, a0, a1, a2);
        ld3(g1, y0, X, k0, k1, k2);
        rp[1] = mk_grow(gray4(a0, a1, a2), lane);
        rg[1] = mk_grow(gray4(k0, k1, k2), lane);
    }

    float s = 0.f;
    #pragma unroll
    for (int k = 0; k < RROWS; ++k) {
        const int ti = k % 3, mi = (k + 1) % 3, bi = (k + 2) % 3;
        const int y  = y0 + k;

        // ---- loads for this iter: bottom gray row y+1, center row y ----
        float4 pb0, pb1, pb2, gb0, gb1, gb2;   // p1/g1 row y+1
        float4 pc0, pc1, pc2, gc0, gc1, gc2;   // p2/g2 row y
        ld3(p1, y + 1, X, pb0, pb1, pb2);
        ld3(g1, y + 1, X, gb0, gb1, gb2);
        ld3(p2, y, X, pc0, pc1, pc2);
        ld3(g2, y, X, gc0, gc1, gc2);

        // motion mag row y: gt raw channels (k* = row y, loaded last iter)
        float mmA[4];
        mmA[0] = (fabsf(gc0.x - k0.x) + fabsf(gc1.x - k1.x) + fabsf(gc2.x - k2.x)) * (1.f / 3.f);
        mmA[1] = (fabsf(gc0.y - k0.y) + fabsf(gc1.y - k1.y) + fabsf(gc2.y - k2.y)) * (1.f / 3.f);
        mmA[2] = (fabsf(gc0.z - k0.z) + fabsf(gc1.z - k1.z) + fabsf(gc2.z - k2.z)) * (1.f / 3.f);
        mmA[3] = (fabsf(gc0.w - k0.w) + fabsf(gc1.w - k1.w) + fabsf(gc2.w - k2.w)) * (1.f / 3.f);

        // gray(t+1) center rows
        const float4 gp2c = gray4(pc0, pc1, pc2);
        const float4 gg2c = gray4(gc0, gc1, gc2);

        // bottom gray rows into rolling slot; rotate g1 raw keep (row y+1)
        rp[bi] = mk_grow(gray4(pb0, pb1, pb2), lane);
        rg[bi] = mk_grow(gray4(gb0, gb1, gb2), lane);
        k0 = gb0; k1 = gb1; k2 = gb2;

        // ---- Sobel + flow + loss for output row y ----
        float up[4], vp[4];
        {
            float w0[6], w1[6], w2[6];
            win6(rp[ti], w0); win6(rp[mi], w1); win6(rp[bi], w2);
            const float gA[4] = {gp2c.x, gp2c.y, gp2c.z, gp2c.w};
            #pragma unroll
            for (int j = 0; j < 4; ++j) {
                const float Ix = (w0[j] - w0[j + 2]) + 2.0f * (w1[j] - w1[j + 2]) + (w2[j] - w2[j + 2]);
                const float Iy = (w0[j] + 2.0f * w0[j + 1] + w0[j + 2])
                               - (w2[j] + 2.0f * w2[j + 1] + w2[j + 2]);
                const float It = gA[j] - w1[j + 1];
                const float inv = 1.0f / (Ix * Ix + Iy * Iy + EPS);
                up[j] = -(Ix * It) * inv;
                vp[j] = -(Iy * It) * inv;
            }
        }
        {
            float w0[6], w1[6], w2[6];
            win6(rg[ti], w0); win6(rg[mi], w1); win6(rg[bi], w2);
            const float gA[4] = {gg2c.x, gg2c.y, gg2c.z, gg2c.w};
            #pragma unroll
            for (int j = 0; j < 4; ++j) {
                const float Ix = (w0[j] - w0[j + 2]) + 2.0f * (w1[j] - w1[j + 2]) + (w2[j] - w2[j + 2]);
                const float Iy = (w0[j] + 2.0f * w0[j + 1] + w0[j + 2])
                               - (w2[j] + 2.0f * w2[j + 1] + w2[j + 2]);
                const float It = gA[j] - w1[j + 1];
                const float inv = 1.0f / (Ix * Ix + Iy * Iy + EPS);
                s += (fabsf(up[j] + (Ix * It) * inv) + fabsf(vp[j] + (Iy * It) * inv)) * mmA[j];
            }
        }
    }

    // ---- wave reduction -> one partial per wave-item (no barrier) ----
    #pragma unroll
    for (int off = 32; off > 0; off >>= 1) s += __shfl_down(s, off, 64);
    if (lane == 0) partial[item] = s;
}

__global__ __launch_bounds__(896) void reduce_kernel(
    const float* __restrict__ partial, float* __restrict__ out)
{
    const float4 v = ld4(partial + threadIdx.x * 4);   // 3584 floats total
    float s = (v.x + v.y) + (v.z + v.w);
    #pragma unroll
    for (int off = 32; off > 0; off >>= 1) s += __shfl_down(s, off, 64);

    __shared__ float wsum[14];
    if ((threadIdx.x & 63) == 0) wsum[threadIdx.x >> 6] = s;
    __syncthreads();
    if (threadIdx.x == 0) {
        float tot = 0.f;
        #pragma unroll
        for (int i = 0; i < 14; ++i) tot += wsum[i];
        out[0] = tot * INV_N;
    }
}

extern "C" void kernel_launch(void* const* d_in, const int* in_sizes, int n_in,
                              void* d_out, int out_size, void* d_ws, size_t ws_size,
                              hipStream_t stream) {
    const float* pred = (const float*)d_in[0];
    const float* gt   = (const float*)d_in[1];
    float* partial    = (float*)d_ws;     // NITEM floats = 14336 B
    float* out        = (float*)d_out;

    flow_loss_kernel<<<dim3(NBLK), dim3(256), 0, stream>>>(pred, gt, partial);
    reduce_kernel<<<1, 896, 0, stream>>>(partial, out);
}

// Round 7
// 124.094 us; speedup vs baseline: 1.4015x; 1.4015x over previous
//
#include <hip/hip_runtime.h>

// Frames [B, T, C, H, W] = [8, 8, 3, 256, 256] fp32
#define BB 8
#define TT 8
#define NPAIR (TT - 1)               // 7
#define HH 256
#define WW 256
#define FRAME_PIX (HH * WW)
#define RROWS 4                      // rows per wave-item
#define NSTRIP (HH / RROWS)          // 64 strips per frame pair
#define NITEM (BB * NPAIR * NSTRIP)  // 3584 wave items
#define NBLK (NITEM / 4)             // 896 blocks x 4 waves
#define EPS 1e-3f
#define INV_N (1.0f / (float)((size_t)BB * NPAIR * 2 * HH * WW))

__device__ __forceinline__ float4 ld4(const float* __restrict__ p) {
    return *reinterpret_cast<const float4*>(p);
}
__device__ __forceinline__ float4 gray4(const float4 r, const float4 g, const float4 b) {
    float4 o;
    o.x = 0.2989f * r.x + 0.587f * g.x + 0.114f * b.x;
    o.y = 0.2989f * r.y + 0.587f * g.y + 0.114f * b.y;
    o.z = 0.2989f * r.z + 0.587f * g.z + 0.114f * b.z;
    o.w = 0.2989f * r.w + 0.587f * g.w + 0.114f * b.w;
    return o;
}

// One gray row per lane: 4 center px (a..d) + left/right halo scalars from
// neighbor lanes via shuffle. NAMED FIELDS ONLY - never array-indexed
// (round-5 lesson: the %3-indexed GRow arrays were demoted to scratch:
// VGPR fell to 64 and 101MB of scratch writes appeared).
struct GRow { float l, a, b, c, d, r; };

__device__ __forceinline__ GRow mk_grow(const float4 g, const int lane) {
    GRow o;
    o.a = g.x; o.b = g.y; o.c = g.z; o.d = g.w;
    const float lw = __shfl_up(g.w, 1, 64);
    const float rx = __shfl_down(g.x, 1, 64);
    o.l = (lane == 0) ? 0.f : lw;
    o.r = (lane == 63) ? 0.f : rx;
    return o;
}

// Load 3 channels of one row (4 px per lane); wave-uniform validity check
// implements the conv zero padding for rows outside the image.
__device__ __forceinline__ void ld3(const float* __restrict__ base, const int y,
                                    const int X, float4& c0, float4& c1, float4& c2) {
    if ((unsigned)y < (unsigned)HH) {
        const float* q = base + (size_t)y * WW + X;
        c0 = ld4(q); c1 = ld4(q + FRAME_PIX); c2 = ld4(q + 2 * FRAME_PIX);
    } else {
        c0 = make_float4(0.f, 0.f, 0.f, 0.f); c1 = c0; c2 = c0;
    }
}

// Flow at one output pixel: window fields f0,f1,f2 of rows T/M/B.
// Pred image: store u,v.  Gt image: accumulate loss (same op order as the
// previously-passing kernels).
#define FLOWJ_P(T, M, Bt, f0, f1, f2, g2v, uj, vj)                              \
    {                                                                           \
        const float Ix = ((T).f0 - (T).f2) + 2.0f * ((M).f0 - (M).f2)           \
                       + ((Bt).f0 - (Bt).f2);                                   \
        const float Iy = ((T).f0 + 2.0f * (T).f1 + (T).f2)                      \
                       - ((Bt).f0 + 2.0f * (Bt).f1 + (Bt).f2);                  \
        const float It = (g2v) - (M).f1;                                        \
        const float inv = 1.0f / (Ix * Ix + Iy * Iy + EPS);                     \
        uj = -(Ix * It) * inv;                                                  \
        vj = -(Iy * It) * inv;                                                  \
    }

#define FLOWJ_G(T, M, Bt, f0, f1, f2, g2v, uj, vj, mmv)                         \
    {                                                                           \
        const float Ix = ((T).f0 - (T).f2) + 2.0f * ((M).f0 - (M).f2)           \
                       + ((Bt).f0 - (Bt).f2);                                   \
        const float Iy = ((T).f0 + 2.0f * (T).f1 + (T).f2)                      \
                       - ((Bt).f0 + 2.0f * (Bt).f1 + (Bt).f2);                  \
        const float It = (g2v) - (M).f1;                                        \
        const float inv = 1.0f / (Ix * Ix + Iy * Iy + EPS);                     \
        s += (fabsf((uj) + (Ix * It) * inv) + fabsf((vj) + (Iy * It) * inv))    \
             * (mmv);                                                           \
    }

// One output row ROWY: 12 float4 loads, mm, gray, Sobel both images, rotate.
// (Parameter deliberately named ROWY: a parameter named 'y' would be
// substituted into the .y vector-field accesses by the preprocessor.)
#define STEP(ROWY)                                                              \
    {                                                                           \
        float4 pb0, pb1, pb2, gb0, gb1, gb2, pc0, pc1, pc2, gc0, gc1, gc2;      \
        ld3(p1, (ROWY) + 1, X, pb0, pb1, pb2);                                  \
        ld3(g1, (ROWY) + 1, X, gb0, gb1, gb2);                                  \
        ld3(p2, (ROWY), X, pc0, pc1, pc2);                                      \
        ld3(g2, (ROWY), X, gc0, gc1, gc2);                                      \
        const float mm0 = (fabsf(gc0.x - k0.x) + fabsf(gc1.x - k1.x)            \
                         + fabsf(gc2.x - k2.x)) * (1.f / 3.f);                  \
        const float mm1 = (fabsf(gc0.y - k0.y) + fabsf(gc1.y - k1.y)            \
                         + fabsf(gc2.y - k2.y)) * (1.f / 3.f);                  \
        const float mm2 = (fabsf(gc0.z - k0.z) + fabsf(gc1.z - k1.z)            \
                         + fabsf(gc2.z - k2.z)) * (1.f / 3.f);                  \
        const float mm3 = (fabsf(gc0.w - k0.w) + fabsf(gc1.w - k1.w)            \
                         + fabsf(gc2.w - k2.w)) * (1.f / 3.f);                  \
        const float4 gp2c = gray4(pc0, pc1, pc2);                               \
        const float4 gg2c = gray4(gc0, gc1, gc2);                               \
        const GRow pB = mk_grow(gray4(pb0, pb1, pb2), lane);                    \
        const GRow gB = mk_grow(gray4(gb0, gb1, gb2), lane);                    \
        k0 = gb0; k1 = gb1; k2 = gb2;                                           \
        float u0, u1, u2, u3, v0, v1, v2, v3;                                   \
        FLOWJ_P(pT, pM, pB, l, a, b, gp2c.x, u0, v0)                            \
        FLOWJ_P(pT, pM, pB, a, b, c, gp2c.y, u1, v1)                            \
        FLOWJ_P(pT, pM, pB, b, c, d, gp2c.z, u2, v2)                            \
        FLOWJ_P(pT, pM, pB, c, d, r, gp2c.w, u3, v3)                            \
        FLOWJ_G(gT, gM, gB, l, a, b, gg2c.x, u0, v0, mm0)                       \
        FLOWJ_G(gT, gM, gB, a, b, c, gg2c.y, u1, v1, mm1)                       \
        FLOWJ_G(gT, gM, gB, b, c, d, gg2c.z, u2, v2, mm2)                       \
        FLOWJ_G(gT, gM, gB, c, d, r, gg2c.w, u3, v3, mm3)                       \
        pT = pM; pM = pB;                                                       \
        gT = gM; gM = gB;                                                       \
    }

// Barrier-free flow loss: one WAVE per (batch, pair, 4-row strip).
// 64 lanes x 4 px span the full 256-px row. Zero LDS, zero __syncthreads:
// waves free-run so the CU's resident waves keep the memory pipe
// continuously busy (the block-phase versions pinned at ~40us with the
// pipe idle through every compute cohort). Straight-line body (macro x4),
// all state in named scalars -> nothing can be demoted to scratch.
// __launch_bounds__(256, 2): 256-VGPR cap, est. live ~130-200.
__global__ __launch_bounds__(256, 2) void flow_loss_kernel(
    const float* __restrict__ pred, const float* __restrict__ gt,
    float* __restrict__ partial)
{
    const int tid   = threadIdx.x;
    const int lane  = tid & 63;
    const int item  = blockIdx.x * 4 + (tid >> 6);   // 0..3583
    const int strip = item & (NSTRIP - 1);
    const int pbt   = item >> 6;                     // 0..55
    const int b     = pbt / NPAIR;
    const int t     = pbt - b * NPAIR;

    const size_t fs = (size_t)3 * FRAME_PIX;
    const float* p1 = pred + ((size_t)b * TT + t) * fs;
    const float* g1 = gt   + ((size_t)b * TT + t) * fs;
    const float* p2 = p1 + fs;
    const float* g2 = g1 + fs;

    const int X  = lane * 4;
    const int y0 = strip * RROWS;

    GRow pT, pM, gT, gM;        // rolling gray rows (top, mid) pred/gt
    float4 k0, k1, k2;          // raw gt(t) channels of current output row

    // ---- prologue: gray rows y0-1 (top) and y0 (mid) ----
    {
        float4 a0, a1, a2, c0, c1, c2;
        ld3(p1, y0 - 1, X, a0, a1, a2);
        ld3(g1, y0 - 1, X, c0, c1, c2);
        pT = mk_grow(gray4(a0, a1, a2), lane);
        gT = mk_grow(gray4(c0, c1, c2), lane);
        ld3(p1, y0, X, a0, a1, a2);
        ld3(g1, y0, X, k0, k1, k2);
        pM = mk_grow(gray4(a0, a1, a2), lane);
        gM = mk_grow(gray4(k0, k1, k2), lane);
    }

    float s = 0.f;
    STEP(y0)
    STEP(y0 + 1)
    STEP(y0 + 2)
    STEP(y0 + 3)

    // ---- wave reduction -> one partial per wave-item (no barrier) ----
    #pragma unroll
    for (int off = 32; off > 0; off >>= 1) s += __shfl_down(s, off, 64);
    if (lane == 0) partial[item] = s;
}

__global__ __launch_bounds__(896) void reduce_kernel(
    const float* __restrict__ partial, float* __restrict__ out)
{
    const float4 v = ld4(partial + threadIdx.x * 4);   // 3584 floats total
    float s = (v.x + v.y) + (v.z + v.w);
    #pragma unroll
    for (int off = 32; off > 0; off >>= 1) s += __shfl_down(s, off, 64);

    __shared__ float wsum[14];
    if ((threadIdx.x & 63) == 0) wsum[threadIdx.x >> 6] = s;
    __syncthreads();
    if (threadIdx.x == 0) {
        float tot = 0.f;
        #pragma unroll
        for (int i = 0; i < 14; ++i) tot += wsum[i];
        out[0] = tot * INV_N;
    }
}

extern "C" void kernel_launch(void* const* d_in, const int* in_sizes, int n_in,
                              void* d_out, int out_size, void* d_ws, size_t ws_size,
                              hipStream_t stream) {
    const float* pred = (const float*)d_in[0];
    const float* gt   = (const float*)d_in[1];
    float* partial    = (float*)d_ws;     // NITEM floats = 14336 B
    float* out        = (float*)d_out;

    flow_loss_kernel<<<dim3(NBLK), dim3(256), 0, stream>>>(pred, gt, partial);
    reduce_kernel<<<1, 896, 0, stream>>>(partial, out);
}